// Round 4
// baseline (132.085 us; speedup 1.0000x reference)
//
#include <hip/hip_runtime.h>
#include <hip/hip_bf16.h>

// Problem constants (from reference)
#define M_TOTAL 131072
#define K_DIM   512
#define N_RANK  256
#define NSEG    1024
#define KC      64            // k-chunk staged in LDS
#define NKC     (K_DIM / KC)  // 8

typedef __attribute__((ext_vector_type(8))) short bf16x8;
typedef __attribute__((ext_vector_type(4))) float f32x4;

// Raw barrier: lgkmcnt(0) for LDS visibility, but DO NOT drain vmcnt --
// keeps the depth-2 global A-prefetch in flight across the barrier.
// (__syncthreads() would emit s_waitcnt vmcnt(0) and kill the pipeline.)
#define BAR() do { \
    asm volatile("s_waitcnt lgkmcnt(0)" ::: "memory"); \
    __builtin_amdgcn_s_barrier(); \
} while (0)

__device__ inline short f2b(float f) {
    __hip_bfloat16 h = __float2bfloat16(f);
    return __builtin_bit_cast(short, h);
}

// CAS-based atomic multiply (device scope, cross-XCD safe)
__device__ inline void atomicMulF(float* p, float v) {
    unsigned int* ip = reinterpret_cast<unsigned int*>(p);
    unsigned int old = *ip;
    unsigned int assumed;
    do {
        assumed = old;
        float nv = __uint_as_float(assumed) * v;
        old = atomicCAS(ip, assumed, __float_as_uint(nv));
    } while (old != assumed);
}

// fast tanh: t = sign(z) * (1 - 2/(e^{2|z|}+1))
__device__ inline float fast_tanh(float z) {
    float e = __expf(2.0f * fabsf(z));
    return copysignf(1.0f - 2.0f / (e + 1.0f), z);
}

// Kernel 1: init out to 1.0 (segment_prod identity) + convert W to bf16 in ws
__global__ void prep_kernel(const float* __restrict__ W,
                            __hip_bfloat16* __restrict__ Wb,
                            float* __restrict__ out) {
    int i = blockIdx.x * 256 + threadIdx.x;
    out[i] = 1.0f;
    if (i < N_RANK * K_DIM) Wb[i] = __float2bfloat16(W[i]);
}

// Kernel 2: fused GEMM(bf16 MFMA, LDS-staged A, depth-2 prefetch, raw barriers)
//           + bias + tanh + segmented product
// Block: 256 threads (4 waves). Block owns 64 rows of x, full 256 cols.
// Wave w computes 64 rows x cols [w*64, w*64+64).
// A-tile: 64x64 bf16 in LDS, double-buffered, XOR-swizzled (byte ^= (row&7)<<4).
// Pipeline at iter kc: BAR; issue B(kc) [L2]; issue A(kc+2) [HBM];
//   cvt+ds_write A(kc+1) (loads a full iteration old); ds_read+MFMA chunk kc.
// Global loads stay in flight across BAR (no vmcnt drain).
__launch_bounds__(256, 4)
__global__ void fused_kernel(const float* __restrict__ x,
                             const __hip_bfloat16* __restrict__ Wb,
                             const float* __restrict__ bias,
                             const int* __restrict__ seg,
                             float* __restrict__ out) {
    const int tid  = threadIdx.x;
    const int wave = tid >> 6;
    const int lane = tid & 63;
    const int l16  = lane & 15;
    const int g    = lane >> 4;       // 0..3 (k-group)
    const int m0   = blockIdx.x * 64;
    const int n0   = wave * 64;

    // LDS: A double-buffer (2 x 64 x 64 bf16 = 16 KB) aliased with the
    // epilogue staging buffer tl (16 rows x 258 f32 = 16512 B).
    __shared__ alignas(16) char smem[16640];
    float* tl = reinterpret_cast<float*>(smem);
    __shared__ int segs[64];

    if (tid < 64) segs[tid] = seg[m0 + tid];

    // staging geometry: thread t covers row (t>>4)+i*16, f32 cols (t&15)*4..+3
    const int srow = tid >> 4;        // 0..15
    const int scol = (tid & 15) * 4;  // f32 element col within chunk
    const int swb  = (tid & 15) * 8;  // byte col within 128-B bf16 row

    f32x4 acc[4][4] = {};             // [m-frag][n-frag]
    f32x4 ra[2][4];                   // A prefetch regs, 2 chunks deep

    // ---- prologue: issue chunk0 + chunk1, stage chunk0 into LDS buf 0 ----
    #pragma unroll
    for (int i = 0; i < 4; ++i)
        ra[0][i] = *reinterpret_cast<const f32x4*>(
            x + (size_t)(m0 + srow + i * 16) * K_DIM + scol);
    #pragma unroll
    for (int i = 0; i < 4; ++i)
        ra[1][i] = *reinterpret_cast<const f32x4*>(
            x + (size_t)(m0 + srow + i * 16) * K_DIM + KC + scol);
    #pragma unroll
    for (int i = 0; i < 4; ++i) {
        const int row  = srow + i * 16;
        const int byte = row * 128 + (swb ^ ((row & 7) << 4));
        short4 p;
        p.x = f2b(ra[0][i][0]); p.y = f2b(ra[0][i][1]);
        p.z = f2b(ra[0][i][2]); p.w = f2b(ra[0][i][3]);
        *reinterpret_cast<short4*>(smem + byte) = p;
    }

    // ---- K loop: 8 chunks of 64, depth-2 pipelined, fully unrolled ----
    #pragma unroll
    for (int kc = 0; kc < NKC; ++kc) {
        BAR();   // chunk kc's LDS writes visible; buf (kc+1)&1 free to write

        // 1) B fragments for this chunk (L2-resident). Issued FIRST so the
        //    MFMA's vmcnt wait for B leaves the newer A-loads in flight.
        bf16x8 bfr[2][4];
        #pragma unroll
        for (int s = 0; s < 2; ++s)
            #pragma unroll
            for (int j = 0; j < 4; ++j)
                bfr[s][j] = *reinterpret_cast<const bf16x8*>(
                    Wb + (size_t)(n0 + j * 16 + l16) * K_DIM + kc * KC + s * 32 + g * 8);

        // 2) issue A loads for chunk kc+2 into slot kc&1 (freed last iter)
        if (kc + 2 < NKC) {
            #pragma unroll
            for (int i = 0; i < 4; ++i)
                ra[kc & 1][i] = *reinterpret_cast<const f32x4*>(
                    x + (size_t)(m0 + srow + i * 16) * K_DIM + (kc + 2) * KC + scol);
        }

        // 3) cvt + ds_write chunk kc+1 (its loads are a full iteration old)
        if (kc + 1 < NKC) {
            #pragma unroll
            for (int i = 0; i < 4; ++i) {
                const int row  = srow + i * 16;
                const int byte = ((kc + 1) & 1) * 8192 + row * 128 + (swb ^ ((row & 7) << 4));
                short4 p;
                p.x = f2b(ra[(kc + 1) & 1][i][0]); p.y = f2b(ra[(kc + 1) & 1][i][1]);
                p.z = f2b(ra[(kc + 1) & 1][i][2]); p.w = f2b(ra[(kc + 1) & 1][i][3]);
                *reinterpret_cast<short4*>(smem + byte) = p;
            }
        }

        // 4) compute chunk kc from LDS buf kc&1
        #pragma unroll
        for (int s = 0; s < 2; ++s) {
            bf16x8 afr[4];
            #pragma unroll
            for (int i = 0; i < 4; ++i) {
                const int row  = i * 16 + l16;
                const int byte = (kc & 1) * 8192 + row * 128 +
                                 ((s * 64 + g * 16) ^ ((row & 7) << 4));
                afr[i] = *reinterpret_cast<const bf16x8*>(smem + byte);
            }
            #pragma unroll
            for (int i = 0; i < 4; ++i)
                #pragma unroll
                for (int j = 0; j < 4; ++j)
                    acc[i][j] = __builtin_amdgcn_mfma_f32_16x16x32_bf16(
                        afr[i], bfr[s][j], acc[i][j], 0, 0, 0);
        }
    }

    // ---- epilogue: bias + tanh in regs ----
    // D layout: col = lane&15, row(within 16x16) = (lane>>4)*4 + r
    #pragma unroll
    for (int j = 0; j < 4; ++j) {
        const float bj = bias[n0 + j * 16 + l16];
        #pragma unroll
        for (int i = 0; i < 4; ++i)
            #pragma unroll
            for (int r = 0; r < 4; ++r)
                acc[i][j][r] = fast_tanh(acc[i][j][r] + bj);
    }

    // ---- segmented product over the block's 64 rows, 16-row phases ----
    int   curSeg = segs[0];
    float prod   = 1.0f;
    const int col = tid;              // one column per thread

    #pragma unroll
    for (int ph = 0; ph < 4; ++ph) {
        BAR();                        // previous phase (K-loop or walk) done
        // stage rows [ph*16, ph*16+16): m-frag i = ph
        #pragma unroll
        for (int j = 0; j < 4; ++j) {
            const int c = n0 + j * 16 + l16;
            #pragma unroll
            for (int r = 0; r < 4; ++r)
                tl[(g * 4 + r) * 258 + c] = acc[ph][j][r];
        }
        BAR();

        for (int r = 0; r < 16; ++r) {
            const int s = segs[ph * 16 + r];
            if (s != curSeg) {
                atomicMulF(&out[(size_t)curSeg * N_RANK + col], prod);
                prod   = 1.0f;
                curSeg = s;
            }
            prod *= tl[r * 258 + col];
        }
    }
    atomicMulF(&out[(size_t)curSeg * N_RANK + col], prod);
}

extern "C" void kernel_launch(void* const* d_in, const int* in_sizes, int n_in,
                              void* d_out, int out_size, void* d_ws, size_t ws_size,
                              hipStream_t stream) {
    const float* x   = (const float*)d_in[0];
    const float* W   = (const float*)d_in[1];
    const float* b   = (const float*)d_in[2];
    const int*   seg = (const int*)d_in[3];
    float*       out = (float*)d_out;
    __hip_bfloat16* Wb = (__hip_bfloat16*)d_ws;

    prep_kernel<<<(NSEG * N_RANK) / 256, 256, 0, stream>>>(W, Wb, out);
    fused_kernel<<<M_TOTAL / 64, 256, 0, stream>>>(x, Wb, b, seg, out);
}

// Round 5
// 115.706 us; speedup vs baseline: 1.1416x; 1.1416x over previous
//
#include <hip/hip_runtime.h>
#include <hip/hip_bf16.h>

// Problem constants (from reference)
#define M_TOTAL 131072
#define K_DIM   512
#define N_RANK  256
#define NSEG    1024
#define KC      64            // k-chunk staged in LDS
#define NKC     (K_DIM / KC)  // 8

typedef __attribute__((ext_vector_type(8))) short bf16x8;
typedef __attribute__((ext_vector_type(4))) float f32x4;

// Raw barrier: lgkmcnt(0) for LDS visibility, but DO NOT drain vmcnt --
// keeps the depth-2 global A-prefetch in flight across the barrier.
// (__syncthreads() would emit s_waitcnt vmcnt(0) and kill the pipeline.)
#define BAR() do { \
    asm volatile("s_waitcnt lgkmcnt(0)" ::: "memory"); \
    __builtin_amdgcn_s_barrier(); \
} while (0)

__device__ inline short f2b(float f) {
    __hip_bfloat16 h = __float2bfloat16(f);
    return __builtin_bit_cast(short, h);
}

// CAS-based atomic multiply (device scope, cross-XCD safe)
__device__ inline void atomicMulF(float* p, float v) {
    unsigned int* ip = reinterpret_cast<unsigned int*>(p);
    unsigned int old = *ip;
    unsigned int assumed;
    do {
        assumed = old;
        float nv = __uint_as_float(assumed) * v;
        old = atomicCAS(ip, assumed, __float_as_uint(nv));
    } while (old != assumed);
}

// fast tanh: t = sign(z) * (1 - 2/(e^{2|z|}+1))
__device__ inline float fast_tanh(float z) {
    float e = __expf(2.0f * fabsf(z));
    return copysignf(1.0f - 2.0f / (e + 1.0f), z);
}

// Kernel 1: init out to 1.0 (segment_prod identity) + convert W to bf16 in ws
__global__ void prep_kernel(const float* __restrict__ W,
                            __hip_bfloat16* __restrict__ Wb,
                            float* __restrict__ out) {
    int i = blockIdx.x * 256 + threadIdx.x;
    out[i] = 1.0f;
    if (i < N_RANK * K_DIM) Wb[i] = __float2bfloat16(W[i]);
}

// Kernel 2: fused GEMM(bf16 MFMA, LDS-staged A, depth-2 prefetch, raw barriers)
//           + bias + tanh + segmented product
// Block: 256 threads (4 waves). Block owns 64 rows of x, full 256 cols.
// Wave w computes 64 rows x cols [w*64, w*64+64).
// A-tile: 64x64 bf16 in LDS, double-buffered, XOR-swizzled (byte ^= (row&7)<<4).
// Pipeline at iter kc: BAR; issue B(kc) [L2]; issue A(kc+2) [HBM];
//   cvt+ds_write A(kc+1) (loads a full iteration old); ds_read+MFMA chunk kc.
// Global loads stay in flight across BAR (no vmcnt drain).
// launch_bounds(256,3): 170-reg budget -- (256,4) spilled (R4: VGPR=64,
// WRITE_SIZE 84 MB of scratch traffic, +20 us). Do not raise.
__launch_bounds__(256, 3)
__global__ void fused_kernel(const float* __restrict__ x,
                             const __hip_bfloat16* __restrict__ Wb,
                             const float* __restrict__ bias,
                             const int* __restrict__ seg,
                             float* __restrict__ out) {
    const int tid  = threadIdx.x;
    const int wave = tid >> 6;
    const int lane = tid & 63;
    const int l16  = lane & 15;
    const int g    = lane >> 4;       // 0..3 (k-group)
    const int m0   = blockIdx.x * 64;
    const int n0   = wave * 64;

    // LDS: A double-buffer (2 x 64 x 64 bf16 = 16 KB) aliased with the
    // epilogue staging buffer tl (16 rows x 258 f32 = 16512 B).
    __shared__ alignas(16) char smem[16640];
    float* tl = reinterpret_cast<float*>(smem);
    __shared__ int segs[64];

    if (tid < 64) segs[tid] = seg[m0 + tid];

    // staging geometry: thread t covers row (t>>4)+i*16, f32 cols (t&15)*4..+3
    const int srow = tid >> 4;        // 0..15
    const int scol = (tid & 15) * 4;  // f32 element col within chunk
    const int swb  = (tid & 15) * 8;  // byte col within 128-B bf16 row

    f32x4 acc[4][4] = {};             // [m-frag][n-frag]
    f32x4 ra[2][4];                   // A prefetch regs, 2 chunks deep

    // ---- prologue: issue chunk0 + chunk1, stage chunk0 into LDS buf 0 ----
    #pragma unroll
    for (int i = 0; i < 4; ++i)
        ra[0][i] = *reinterpret_cast<const f32x4*>(
            x + (size_t)(m0 + srow + i * 16) * K_DIM + scol);
    #pragma unroll
    for (int i = 0; i < 4; ++i)
        ra[1][i] = *reinterpret_cast<const f32x4*>(
            x + (size_t)(m0 + srow + i * 16) * K_DIM + KC + scol);
    #pragma unroll
    for (int i = 0; i < 4; ++i) {
        const int row  = srow + i * 16;
        const int byte = row * 128 + (swb ^ ((row & 7) << 4));
        short4 p;
        p.x = f2b(ra[0][i][0]); p.y = f2b(ra[0][i][1]);
        p.z = f2b(ra[0][i][2]); p.w = f2b(ra[0][i][3]);
        *reinterpret_cast<short4*>(smem + byte) = p;
    }

    // ---- K loop: 8 chunks of 64, depth-2 pipelined, fully unrolled ----
    #pragma unroll
    for (int kc = 0; kc < NKC; ++kc) {
        BAR();   // chunk kc's LDS writes visible; buf (kc+1)&1 free to write

        // 1) B fragments for this chunk (L2-resident). Issued FIRST so the
        //    MFMA's vmcnt wait for B leaves the newer A-loads in flight.
        bf16x8 bfr[2][4];
        #pragma unroll
        for (int s = 0; s < 2; ++s)
            #pragma unroll
            for (int j = 0; j < 4; ++j)
                bfr[s][j] = *reinterpret_cast<const bf16x8*>(
                    Wb + (size_t)(n0 + j * 16 + l16) * K_DIM + kc * KC + s * 32 + g * 8);

        // 2) issue A loads for chunk kc+2 into slot kc&1 (freed last iter)
        if (kc + 2 < NKC) {
            #pragma unroll
            for (int i = 0; i < 4; ++i)
                ra[kc & 1][i] = *reinterpret_cast<const f32x4*>(
                    x + (size_t)(m0 + srow + i * 16) * K_DIM + (kc + 2) * KC + scol);
        }

        // 3) cvt + ds_write chunk kc+1 (its loads are a full iteration old)
        if (kc + 1 < NKC) {
            #pragma unroll
            for (int i = 0; i < 4; ++i) {
                const int row  = srow + i * 16;
                const int byte = ((kc + 1) & 1) * 8192 + row * 128 + (swb ^ ((row & 7) << 4));
                short4 p;
                p.x = f2b(ra[(kc + 1) & 1][i][0]); p.y = f2b(ra[(kc + 1) & 1][i][1]);
                p.z = f2b(ra[(kc + 1) & 1][i][2]); p.w = f2b(ra[(kc + 1) & 1][i][3]);
                *reinterpret_cast<short4*>(smem + byte) = p;
            }
        }

        // 4) compute chunk kc from LDS buf kc&1
        #pragma unroll
        for (int s = 0; s < 2; ++s) {
            bf16x8 afr[4];
            #pragma unroll
            for (int i = 0; i < 4; ++i) {
                const int row  = i * 16 + l16;
                const int byte = (kc & 1) * 8192 + row * 128 +
                                 ((s * 64 + g * 16) ^ ((row & 7) << 4));
                afr[i] = *reinterpret_cast<const bf16x8*>(smem + byte);
            }
            #pragma unroll
            for (int i = 0; i < 4; ++i)
                #pragma unroll
                for (int j = 0; j < 4; ++j)
                    acc[i][j] = __builtin_amdgcn_mfma_f32_16x16x32_bf16(
                        afr[i], bfr[s][j], acc[i][j], 0, 0, 0);
        }
    }

    // ---- epilogue: bias + tanh in regs ----
    // D layout: col = lane&15, row(within 16x16) = (lane>>4)*4 + r
    #pragma unroll
    for (int j = 0; j < 4; ++j) {
        const float bj = bias[n0 + j * 16 + l16];
        #pragma unroll
        for (int i = 0; i < 4; ++i)
            #pragma unroll
            for (int r = 0; r < 4; ++r)
                acc[i][j][r] = fast_tanh(acc[i][j][r] + bj);
    }

    // ---- segmented product over the block's 64 rows, 16-row phases ----
    int   curSeg = segs[0];
    float prod   = 1.0f;
    const int col = tid;              // one column per thread

    #pragma unroll
    for (int ph = 0; ph < 4; ++ph) {
        BAR();                        // previous phase (K-loop or walk) done
        // stage rows [ph*16, ph*16+16): m-frag i = ph
        #pragma unroll
        for (int j = 0; j < 4; ++j) {
            const int c = n0 + j * 16 + l16;
            #pragma unroll
            for (int r = 0; r < 4; ++r)
                tl[(g * 4 + r) * 258 + c] = acc[ph][j][r];
        }
        BAR();

        for (int r = 0; r < 16; ++r) {
            const int s = segs[ph * 16 + r];
            if (s != curSeg) {
                atomicMulF(&out[(size_t)curSeg * N_RANK + col], prod);
                prod   = 1.0f;
                curSeg = s;
            }
            prod *= tl[r * 258 + col];
        }
    }
    atomicMulF(&out[(size_t)curSeg * N_RANK + col], prod);
}

extern "C" void kernel_launch(void* const* d_in, const int* in_sizes, int n_in,
                              void* d_out, int out_size, void* d_ws, size_t ws_size,
                              hipStream_t stream) {
    const float* x   = (const float*)d_in[0];
    const float* W   = (const float*)d_in[1];
    const float* b   = (const float*)d_in[2];
    const int*   seg = (const int*)d_in[3];
    float*       out = (float*)d_out;
    __hip_bfloat16* Wb = (__hip_bfloat16*)d_ws;

    prep_kernel<<<(NSEG * N_RANK) / 256, 256, 0, stream>>>(W, Wb, out);
    fused_kernel<<<M_TOTAL / 64, 256, 0, stream>>>(x, Wb, b, seg, out);
}

// Round 6
// 115.481 us; speedup vs baseline: 1.1438x; 1.0019x over previous
//
#include <hip/hip_runtime.h>
#include <hip/hip_bf16.h>
#include <stdint.h>

// Problem constants (from reference)
#define M_TOTAL 131072
#define K_DIM   512
#define N_RANK  256
#define NSEG    1024
#define KC      64            // k-chunk staged in LDS (64 f32 per row)
#define NKC     (K_DIM / KC)  // 8

typedef __attribute__((ext_vector_type(8))) short bf16x8;
typedef __attribute__((ext_vector_type(4))) float f32x4;

// Raw barrier: lgkmcnt(0) for LDS visibility, vmcnt NOT drained --
// DMA staging loads stay in flight across the barrier (T3/T4 pattern).
#define BAR() do { \
    asm volatile("s_waitcnt lgkmcnt(0)" ::: "memory"); \
    __builtin_amdgcn_s_barrier(); \
} while (0)

__device__ inline short f2b(float f) {
    __hip_bfloat16 h = __float2bfloat16(f);
    return __builtin_bit_cast(short, h);
}

// CAS-based atomic multiply (device scope, cross-XCD safe)
__device__ inline void atomicMulF(float* p, float v) {
    unsigned int* ip = reinterpret_cast<unsigned int*>(p);
    unsigned int old = *ip;
    unsigned int assumed;
    do {
        assumed = old;
        float nv = __uint_as_float(assumed) * v;
        old = atomicCAS(ip, assumed, __float_as_uint(nv));
    } while (old != assumed);
}

// fast tanh: t = sign(z) * (1 - 2/(e^{2|z|}+1))
__device__ inline float fast_tanh(float z) {
    float e = __expf(2.0f * fabsf(z));
    return copysignf(1.0f - 2.0f / (e + 1.0f), z);
}

// Kernel 1: init out to 1.0 (segment_prod identity) + convert W to bf16 in ws
__global__ void prep_kernel(const float* __restrict__ W,
                            __hip_bfloat16* __restrict__ Wb,
                            float* __restrict__ out) {
    int i = blockIdx.x * 256 + threadIdx.x;
    out[i] = 1.0f;
    if (i < N_RANK * K_DIM) Wb[i] = __float2bfloat16(W[i]);
}

// Kernel 2: fused GEMM + bias + tanh + segmented product.
// x staged as F32 via global_load_lds DMA (async, zero VGPR, counted vmcnt),
// converted to bf16 at LDS-read time. B (Wb) direct from L2.
//
// Block: 256 threads (4 waves). Block owns 64 rows, full 256 cols.
// Wave w computes all 64 rows x cols [w*64, w*64+64).
//
// LDS chunk layout (linear dest for DMA, swizzle applied on the GLOBAL
// source address -- rule: linear dest + inverse-swz source + swz on read):
//   LDS[row*256 + (colbyte ^ ((row&7)<<4))] = x[m0+row][k0 + colbyte/4]
// Read of 16 rows x fixed 16B col then spreads across all banks (floor).
//
// Schedule per chunk kc (T3/T4): BAR1 (prev reads done -> buf free);
//   issue 4 DMA for chunk kc+1; s_waitcnt vmcnt(4) (chunk kc landed, kc+1
//   stays in flight -- never drain to 0 mid-loop); BAR2 (all waves landed);
//   B-loads, ds_read+cvt, 32 MFMA.
__launch_bounds__(256, 3)
__global__ void fused_kernel(const float* __restrict__ x,
                             const __hip_bfloat16* __restrict__ Wb,
                             const float* __restrict__ bias,
                             const int* __restrict__ seg,
                             float* __restrict__ out) {
    const int tid  = threadIdx.x;
    const int wave = tid >> 6;
    const int lane = tid & 63;
    const int l16  = lane & 15;
    const int g    = lane >> 4;       // 0..3 (k-group)
    const int m0   = blockIdx.x * 64;
    const int n0   = wave * 64;

    // LDS: A double-buffer 2 x (64 rows x 256B f32) = 32 KB; epilogue tl
    // (16 x 258 f32 = 16512 B) aliases the same space after the K loop.
    __shared__ alignas(16) char smem[32768];
    float* tl = reinterpret_cast<float*>(smem);
    __shared__ int segs[64];

    if (tid < 64) segs[tid] = seg[m0 + tid];

    // ---- DMA geometry ----
    // 16 DMA instrs per chunk (1 KB each = 4 rows); wave w issues t=0..3,
    // covering rows 16w+4t .. +3. Lane l -> row 16w+4t+(l>>4),
    // source f32 col = ((l&15) ^ r7)*4 (+k0), r7 = (4t+(l>>4))&7.
    const int drow = lane >> 4;               // 0..3 row within 4-row slab
    const int dc16 = lane & 15;               // 16B slot within row

    f32x4 acc[4][4] = {};                     // [m-frag][n-frag]

    #define DMA_CHUNK(kc_, buf_)                                              \
        do {                                                                  \
            _Pragma("unroll")                                                 \
            for (int t = 0; t < 4; ++t) {                                     \
                const int r7   = (4 * t + drow) & 7;                          \
                const int cf   = ((dc16 ^ r7) << 2);  /* f32 col 0..63 */     \
                const float* gsrc = x + (size_t)(m0 + 16 * wave + 4 * t + drow) * K_DIM \
                                      + (kc_) * KC + cf;                      \
                uint32_t* ldst = reinterpret_cast<uint32_t*>(                 \
                    smem + (buf_) * 16384 + (wave * 4 + t) * 1024);           \
                __builtin_amdgcn_global_load_lds(                             \
                    reinterpret_cast<const uint32_t*>(gsrc), ldst, 16, 0, 0); \
            }                                                                 \
        } while (0)

    // ---- prologue: issue chunk 0 into buf 0 ----
    DMA_CHUNK(0, 0);

    // ---- K loop: 8 chunks of 64 ----
    #pragma unroll
    for (int kc = 0; kc < NKC; ++kc) {
        BAR();   // all waves done reading buf (kc+1)&1 (chunk kc-1) -> free

        if (kc + 1 < NKC) {
            DMA_CHUNK(kc + 1, (kc + 1) & 1);
            asm volatile("s_waitcnt vmcnt(4)" ::: "memory");  // chunk kc landed
        } else {
            asm volatile("s_waitcnt vmcnt(0)" ::: "memory");  // drain last
        }
        BAR();   // every wave waited its own DMA -> whole buffer valid

        // B fragments for this chunk (L2-resident)
        bf16x8 bfr[2][4];
        #pragma unroll
        for (int s = 0; s < 2; ++s)
            #pragma unroll
            for (int j = 0; j < 4; ++j)
                bfr[s][j] = *reinterpret_cast<const bf16x8*>(
                    Wb + (size_t)(n0 + j * 16 + l16) * K_DIM + kc * KC + s * 32 + g * 8);

        const int bufb = (kc & 1) * 16384;
        #pragma unroll
        for (int s = 0; s < 2; ++s) {
            bf16x8 afr[4];
            #pragma unroll
            for (int i = 0; i < 4; ++i) {
                const int row = i * 16 + l16;
                const int X   = (l16 & 7) << 4;
                const int c0  = s * 128 + g * 32;
                f32x4 lo = *reinterpret_cast<const f32x4*>(smem + bufb + row * 256 + (c0 ^ X));
                f32x4 hi = *reinterpret_cast<const f32x4*>(smem + bufb + row * 256 + ((c0 + 16) ^ X));
                bf16x8 av;
                av[0] = f2b(lo[0]); av[1] = f2b(lo[1]);
                av[2] = f2b(lo[2]); av[3] = f2b(lo[3]);
                av[4] = f2b(hi[0]); av[5] = f2b(hi[1]);
                av[6] = f2b(hi[2]); av[7] = f2b(hi[3]);
                afr[i] = av;
            }
            #pragma unroll
            for (int i = 0; i < 4; ++i)
                #pragma unroll
                for (int j = 0; j < 4; ++j)
                    acc[i][j] = __builtin_amdgcn_mfma_f32_16x16x32_bf16(
                        afr[i], bfr[s][j], acc[i][j], 0, 0, 0);
        }
    }

    // ---- epilogue: bias + tanh in regs ----
    // D layout: col = lane&15, row(within 16x16) = (lane>>4)*4 + r
    #pragma unroll
    for (int j = 0; j < 4; ++j) {
        const float bj = bias[n0 + j * 16 + l16];
        #pragma unroll
        for (int i = 0; i < 4; ++i)
            #pragma unroll
            for (int r = 0; r < 4; ++r)
                acc[i][j][r] = fast_tanh(acc[i][j][r] + bj);
    }

    // ---- segmented product over the block's 64 rows, 16-row phases ----
    int   curSeg = segs[0];
    float prod   = 1.0f;
    const int col = tid;              // one column per thread

    #pragma unroll
    for (int ph = 0; ph < 4; ++ph) {
        BAR();                        // previous phase (K-loop or walk) done
        #pragma unroll
        for (int j = 0; j < 4; ++j) {
            const int c = n0 + j * 16 + l16;
            #pragma unroll
            for (int r = 0; r < 4; ++r)
                tl[(g * 4 + r) * 258 + c] = acc[ph][j][r];
        }
        BAR();

        for (int r = 0; r < 16; ++r) {
            const int s = segs[ph * 16 + r];
            if (s != curSeg) {
                atomicMulF(&out[(size_t)curSeg * N_RANK + col], prod);
                prod   = 1.0f;
                curSeg = s;
            }
            prod *= tl[r * 258 + col];
        }
    }
    atomicMulF(&out[(size_t)curSeg * N_RANK + col], prod);
}

extern "C" void kernel_launch(void* const* d_in, const int* in_sizes, int n_in,
                              void* d_out, int out_size, void* d_ws, size_t ws_size,
                              hipStream_t stream) {
    const float* x   = (const float*)d_in[0];
    const float* W   = (const float*)d_in[1];
    const float* b   = (const float*)d_in[2];
    const int*   seg = (const int*)d_in[3];
    float*       out = (float*)d_out;
    __hip_bfloat16* Wb = (__hip_bfloat16*)d_ws;

    prep_kernel<<<(NSEG * N_RANK) / 256, 256, 0, stream>>>(W, Wb, out);
    fused_kernel<<<M_TOTAL / 64, 256, 0, stream>>>(x, Wb, b, seg, out);
}

// Round 7
// 114.740 us; speedup vs baseline: 1.1512x; 1.0065x over previous
//
#include <hip/hip_runtime.h>
#include <hip/hip_bf16.h>
#include <stdint.h>

// Problem constants (from reference)
#define M_TOTAL 131072
#define K_DIM   512
#define N_RANK  256
#define NSEG    1024
#define KC      64            // k-chunk staged in LDS (64 f32 per row)
#define NKC     (K_DIM / KC)  // 8
#define NB      (M_TOTAL / 64)  // 2048 pass-1 blocks

typedef __attribute__((ext_vector_type(8))) short bf16x8;
typedef __attribute__((ext_vector_type(4))) float f32x4;

// Raw barrier: lgkmcnt(0) for LDS visibility, vmcnt NOT drained --
// DMA staging loads stay in flight across the barrier (T3/T4 pattern).
#define BAR() do { \
    asm volatile("s_waitcnt lgkmcnt(0)" ::: "memory"); \
    __builtin_amdgcn_s_barrier(); \
} while (0)

__device__ inline short f2b(float f) {
    __hip_bfloat16 h = __float2bfloat16(f);
    return __builtin_bit_cast(short, h);
}

// fast tanh: t = sign(z) * (1 - 2/(e^{2|z|}+1))
__device__ inline float fast_tanh(float z) {
    float e = __expf(2.0f * fabsf(z));
    return copysignf(1.0f - 2.0f / (e + 1.0f), z);
}

// Kernel 1: init out to 1.0 (segment_prod identity for empty segments)
//           + convert W to bf16 in ws
__global__ void prep_kernel(const float* __restrict__ W,
                            __hip_bfloat16* __restrict__ Wb,
                            float* __restrict__ out) {
    int i = blockIdx.x * 256 + threadIdx.x;
    out[i] = 1.0f;
    if (i < N_RANK * K_DIM) Wb[i] = __float2bfloat16(W[i]);
}

// Kernel 2 (pass 1): fused GEMM + bias + tanh + per-block segmented product.
// GEMM identical to R6 (DMA-staged A, counted vmcnt, raw barriers).
// Epilogue (NO atomics): per block over its 64 sorted rows --
//   - segments strictly between first and last: fully contained in this
//     block -> exclusive plain store to out[s].
//   - rows of the block's FIRST segment -> partial[b][0][col];
//     rows of the LAST segment (if different) -> partial[b][1][col].
//     (if segF==segL the whole product lands in partial[b][0].)
// Pass 2 combines boundary partials deterministically.
__launch_bounds__(256, 3)
__global__ void fused_kernel(const float* __restrict__ x,
                             const __hip_bfloat16* __restrict__ Wb,
                             const float* __restrict__ bias,
                             const int* __restrict__ seg,
                             float* __restrict__ out,
                             float* __restrict__ partial) {
    const int tid  = threadIdx.x;
    const int wave = tid >> 6;
    const int lane = tid & 63;
    const int l16  = lane & 15;
    const int g    = lane >> 4;       // 0..3 (k-group)
    const int bid  = blockIdx.x;
    const int m0   = bid * 64;
    const int n0   = wave * 64;

    // LDS: A double-buffer 2 x (64 rows x 256B f32) = 32 KB; epilogue tl
    // (16 x 258 f32 = 16512 B) aliases the same space after the K loop.
    __shared__ alignas(16) char smem[32768];
    float* tl = reinterpret_cast<float*>(smem);
    __shared__ int segs[64];

    if (tid < 64) segs[tid] = seg[m0 + tid];

    // ---- DMA geometry ----
    const int drow = lane >> 4;               // 0..3 row within 4-row slab
    const int dc16 = lane & 15;               // 16B slot within row

    f32x4 acc[4][4] = {};                     // [m-frag][n-frag]

    #define DMA_CHUNK(kc_, buf_)                                              \
        do {                                                                  \
            _Pragma("unroll")                                                 \
            for (int t = 0; t < 4; ++t) {                                     \
                const int r7   = (4 * t + drow) & 7;                          \
                const int cf   = ((dc16 ^ r7) << 2);  /* f32 col 0..63 */     \
                const float* gsrc = x + (size_t)(m0 + 16 * wave + 4 * t + drow) * K_DIM \
                                      + (kc_) * KC + cf;                      \
                uint32_t* ldst = reinterpret_cast<uint32_t*>(                 \
                    smem + (buf_) * 16384 + (wave * 4 + t) * 1024);           \
                __builtin_amdgcn_global_load_lds(                             \
                    reinterpret_cast<const uint32_t*>(gsrc), ldst, 16, 0, 0); \
            }                                                                 \
        } while (0)

    // ---- prologue: issue chunk 0 into buf 0 ----
    DMA_CHUNK(0, 0);

    // ---- K loop: 8 chunks of 64 ----
    #pragma unroll
    for (int kc = 0; kc < NKC; ++kc) {
        BAR();   // all waves done reading buf (kc+1)&1 (chunk kc-1) -> free

        if (kc + 1 < NKC) {
            DMA_CHUNK(kc + 1, (kc + 1) & 1);
            asm volatile("s_waitcnt vmcnt(4)" ::: "memory");  // chunk kc landed
        } else {
            asm volatile("s_waitcnt vmcnt(0)" ::: "memory");  // drain last
        }
        BAR();   // every wave waited its own DMA -> whole buffer valid

        // B fragments for this chunk (L2-resident)
        bf16x8 bfr[2][4];
        #pragma unroll
        for (int s = 0; s < 2; ++s)
            #pragma unroll
            for (int j = 0; j < 4; ++j)
                bfr[s][j] = *reinterpret_cast<const bf16x8*>(
                    Wb + (size_t)(n0 + j * 16 + l16) * K_DIM + kc * KC + s * 32 + g * 8);

        const int bufb = (kc & 1) * 16384;
        #pragma unroll
        for (int s = 0; s < 2; ++s) {
            bf16x8 afr[4];
            #pragma unroll
            for (int i = 0; i < 4; ++i) {
                const int row = i * 16 + l16;
                const int X   = (l16 & 7) << 4;
                const int c0  = s * 128 + g * 32;
                f32x4 lo = *reinterpret_cast<const f32x4*>(smem + bufb + row * 256 + (c0 ^ X));
                f32x4 hi = *reinterpret_cast<const f32x4*>(smem + bufb + row * 256 + ((c0 + 16) ^ X));
                bf16x8 av;
                av[0] = f2b(lo[0]); av[1] = f2b(lo[1]);
                av[2] = f2b(lo[2]); av[3] = f2b(lo[3]);
                av[4] = f2b(hi[0]); av[5] = f2b(hi[1]);
                av[6] = f2b(hi[2]); av[7] = f2b(hi[3]);
                afr[i] = av;
            }
            #pragma unroll
            for (int i = 0; i < 4; ++i)
                #pragma unroll
                for (int j = 0; j < 4; ++j)
                    acc[i][j] = __builtin_amdgcn_mfma_f32_16x16x32_bf16(
                        afr[i], bfr[s][j], acc[i][j], 0, 0, 0);
        }
    }

    // ---- epilogue: bias + tanh in regs ----
    // D layout: col = lane&15, row(within 16x16) = (lane>>4)*4 + r
    #pragma unroll
    for (int j = 0; j < 4; ++j) {
        const float bj = bias[n0 + j * 16 + l16];
        #pragma unroll
        for (int i = 0; i < 4; ++i)
            #pragma unroll
            for (int r = 0; r < 4; ++r)
                acc[i][j][r] = fast_tanh(acc[i][j][r] + bj);
    }

    // ---- segmented product over the block's 64 rows, 16-row phases ----
    // Flush rule (all branches wave-uniform; sorted segs):
    //   run of segF -> partial[b][0]; mid-walk runs (interior) -> out (plain
    //   store, exclusive); final run: segF -> partial[b][0], else partial[b][1].
    const int segF = segs[0];
    int   curSeg = segF;
    float prod   = 1.0f;
    const int col = tid;              // one column per thread

    #pragma unroll
    for (int ph = 0; ph < 4; ++ph) {
        BAR();                        // previous phase (K-loop or walk) done
        #pragma unroll
        for (int j = 0; j < 4; ++j) {
            const int c = n0 + j * 16 + l16;
            #pragma unroll
            for (int r = 0; r < 4; ++r)
                tl[(g * 4 + r) * 258 + c] = acc[ph][j][r];
        }
        BAR();

        for (int r = 0; r < 16; ++r) {
            const int s = segs[ph * 16 + r];
            if (s != curSeg) {
                if (curSeg == segF)
                    partial[(size_t)(bid * 2 + 0) * N_RANK + col] = prod;
                else
                    out[(size_t)curSeg * N_RANK + col] = prod;   // interior: exclusive
                prod   = 1.0f;
                curSeg = s;
            }
            prod *= tl[r * 258 + col];
        }
    }
    if (curSeg == segF)
        partial[(size_t)(bid * 2 + 0) * N_RANK + col] = prod;    // segF==segL case
    else
        partial[(size_t)(bid * 2 + 1) * N_RANK + col] = prod;

    #undef DMA_CHUNK
}

// Kernel 3 (pass 2): combine boundary partials. Block b owns boundary
// segment s iff s first appears in block b (seg[64b-1] < s). Owner multiplies
// its partial with forward blocks' P0 while seg[64*b2]==s, stores out[s].
// Interior segments were already stored by pass 1; empty segments stay 1.0.
__global__ void pass2_kernel(const int* __restrict__ seg,
                             const float* __restrict__ partial,
                             float* __restrict__ out) {
    const int b   = blockIdx.x;
    const int col = threadIdx.x;      // 0..255
    const int sF    = seg[b * 64];
    const int sL    = seg[b * 64 + 63];
    const int prevL = (b == 0) ? -1 : seg[b * 64 - 1];

    if (prevL < sF) {                 // b owns its first segment
        float p = partial[(size_t)(b * 2 + 0) * N_RANK + col];
        for (int b2 = b + 1; b2 < NB && seg[b2 * 64] == sF; ++b2)
            p *= partial[(size_t)(b2 * 2 + 0) * N_RANK + col];
        out[(size_t)sF * N_RANK + col] = p;
    }
    if (sL != sF) {                   // b always owns sL when sL != sF
        float p = partial[(size_t)(b * 2 + 1) * N_RANK + col];
        for (int b2 = b + 1; b2 < NB && seg[b2 * 64] == sL; ++b2)
            p *= partial[(size_t)(b2 * 2 + 0) * N_RANK + col];
        out[(size_t)sL * N_RANK + col] = p;
    }
}

extern "C" void kernel_launch(void* const* d_in, const int* in_sizes, int n_in,
                              void* d_out, int out_size, void* d_ws, size_t ws_size,
                              hipStream_t stream) {
    const float* x   = (const float*)d_in[0];
    const float* W   = (const float*)d_in[1];
    const float* b   = (const float*)d_in[2];
    const int*   seg = (const int*)d_in[3];
    float*       out = (float*)d_out;
    __hip_bfloat16* Wb = (__hip_bfloat16*)d_ws;                       // 256 KB
    float* partial = (float*)((char*)d_ws + (1 << 20));               // 4 MB @ +1MB

    prep_kernel<<<(NSEG * N_RANK) / 256, 256, 0, stream>>>(W, Wb, out);
    fused_kernel<<<NB, 256, 0, stream>>>(x, Wb, b, seg, out, partial);
    pass2_kernel<<<NB, 256, 0, stream>>>(seg, partial, out);
}

// Round 8
// 109.663 us; speedup vs baseline: 1.2045x; 1.0463x over previous
//
#include <hip/hip_runtime.h>
#include <hip/hip_bf16.h>
#include <stdint.h>

// Problem constants (from reference)
#define M_TOTAL 131072
#define K_DIM   512
#define N_RANK  256
#define NSEG    1024
#define KC      64            // k-chunk staged in LDS (64 f32 per row)
#define NKC     (K_DIM / KC)  // 8
#define NB      (M_TOTAL / 64)  // 2048 pass-1 blocks

typedef __attribute__((ext_vector_type(8))) short bf16x8;
typedef __attribute__((ext_vector_type(4))) float f32x4;

// Raw barrier: lgkmcnt(0) for LDS visibility, vmcnt NOT drained --
// DMA staging loads stay in flight across the barrier (T3/T4 pattern).
#define BAR() do { \
    asm volatile("s_waitcnt lgkmcnt(0)" ::: "memory"); \
    __builtin_amdgcn_s_barrier(); \
} while (0)

__device__ inline short f2b(float f) {
    __hip_bfloat16 h = __float2bfloat16(f);
    return __builtin_bit_cast(short, h);
}

// fast tanh: t = sign(z) * (1 - 2/(e^{2|z|}+1))
__device__ inline float fast_tanh(float z) {
    float e = __expf(2.0f * fabsf(z));
    return copysignf(1.0f - 2.0f / (e + 1.0f), z);
}

// Kernel 1: init out to 1.0 (segment_prod identity for empty segments)
//           + convert W to bf16 in ws
__global__ void prep_kernel(const float* __restrict__ W,
                            __hip_bfloat16* __restrict__ Wb,
                            float* __restrict__ out) {
    int i = blockIdx.x * 256 + threadIdx.x;
    out[i] = 1.0f;
    if (i < N_RANK * K_DIM) Wb[i] = __float2bfloat16(W[i]);
}

// Kernel 2 (pass 1): fused GEMM + bias + tanh + IN-REGISTER segmented product.
// GEMM identical to R7 (DMA-staged A, counted vmcnt, raw barriers).
// Epilogue: run boundaries via __ballot -> 64-bit mask; per run, predicated
// per-thread product over its 16 acc rows + 2x shfl_xor cross-g product.
// No LDS, no barriers, no serial walk. Store targets as R7:
//   first run -> partial[b][0]; last run (end==64, start>0) -> partial[b][1];
//   interior runs -> out[s] (exclusive plain store).
__launch_bounds__(256, 3)
__global__ void fused_kernel(const float* __restrict__ x,
                             const __hip_bfloat16* __restrict__ Wb,
                             const float* __restrict__ bias,
                             const int* __restrict__ seg,
                             float* __restrict__ out,
                             float* __restrict__ partial) {
    const int tid  = threadIdx.x;
    const int wave = tid >> 6;
    const int lane = tid & 63;
    const int l16  = lane & 15;
    const int g    = lane >> 4;       // 0..3 (k-group / row-group)
    const int bid  = blockIdx.x;
    const int m0   = bid * 64;
    const int n0   = wave * 64;

    // LDS: A double-buffer only, 2 x (64 rows x 256B f32) = 32 KB.
    __shared__ alignas(16) char smem[32768];

    // ---- DMA geometry ----
    const int drow = lane >> 4;               // 0..3 row within 4-row slab
    const int dc16 = lane & 15;               // 16B slot within row

    f32x4 acc[4][4] = {};                     // [m-frag][n-frag]

    #define DMA_CHUNK(kc_, buf_)                                              \
        do {                                                                  \
            _Pragma("unroll")                                                 \
            for (int t = 0; t < 4; ++t) {                                     \
                const int r7   = (4 * t + drow) & 7;                          \
                const int cf   = ((dc16 ^ r7) << 2);  /* f32 col 0..63 */     \
                const float* gsrc = x + (size_t)(m0 + 16 * wave + 4 * t + drow) * K_DIM \
                                      + (kc_) * KC + cf;                      \
                uint32_t* ldst = reinterpret_cast<uint32_t*>(                 \
                    smem + (buf_) * 16384 + (wave * 4 + t) * 1024);           \
                __builtin_amdgcn_global_load_lds(                             \
                    reinterpret_cast<const uint32_t*>(gsrc), ldst, 16, 0, 0); \
            }                                                                 \
        } while (0)

    // ---- prologue: issue chunk 0 into buf 0 ----
    DMA_CHUNK(0, 0);

    // ---- K loop: 8 chunks of 64 ----
    #pragma unroll
    for (int kc = 0; kc < NKC; ++kc) {
        BAR();   // all waves done reading buf (kc+1)&1 (chunk kc-1) -> free

        if (kc + 1 < NKC) {
            DMA_CHUNK(kc + 1, (kc + 1) & 1);
            asm volatile("s_waitcnt vmcnt(4)" ::: "memory");  // chunk kc landed
        } else {
            asm volatile("s_waitcnt vmcnt(0)" ::: "memory");  // drain last
        }
        BAR();   // every wave waited its own DMA -> whole buffer valid

        // B fragments for this chunk (L2-resident)
        bf16x8 bfr[2][4];
        #pragma unroll
        for (int s = 0; s < 2; ++s)
            #pragma unroll
            for (int j = 0; j < 4; ++j)
                bfr[s][j] = *reinterpret_cast<const bf16x8*>(
                    Wb + (size_t)(n0 + j * 16 + l16) * K_DIM + kc * KC + s * 32 + g * 8);

        const int bufb = (kc & 1) * 16384;
        #pragma unroll
        for (int s = 0; s < 2; ++s) {
            bf16x8 afr[4];
            #pragma unroll
            for (int i = 0; i < 4; ++i) {
                const int row = i * 16 + l16;
                const int X   = (l16 & 7) << 4;
                const int c0  = s * 128 + g * 32;
                f32x4 lo = *reinterpret_cast<const f32x4*>(smem + bufb + row * 256 + (c0 ^ X));
                f32x4 hi = *reinterpret_cast<const f32x4*>(smem + bufb + row * 256 + ((c0 + 16) ^ X));
                bf16x8 av;
                av[0] = f2b(lo[0]); av[1] = f2b(lo[1]);
                av[2] = f2b(lo[2]); av[3] = f2b(lo[3]);
                av[4] = f2b(hi[0]); av[5] = f2b(hi[1]);
                av[6] = f2b(hi[2]); av[7] = f2b(hi[3]);
                afr[i] = av;
            }
            #pragma unroll
            for (int i = 0; i < 4; ++i)
                #pragma unroll
                for (int j = 0; j < 4; ++j)
                    acc[i][j] = __builtin_amdgcn_mfma_f32_16x16x32_bf16(
                        afr[i], bfr[s][j], acc[i][j], 0, 0, 0);
        }
    }
    #undef DMA_CHUNK

    // ---- bias + tanh in regs ----
    // D layout: col = lane&15, row(within 16x16) = (lane>>4)*4 + r
    #pragma unroll
    for (int j = 0; j < 4; ++j) {
        const float bj = bias[n0 + j * 16 + l16];
        #pragma unroll
        for (int i = 0; i < 4; ++i)
            #pragma unroll
            for (int r = 0; r < 4; ++r)
                acc[i][j][r] = fast_tanh(acc[i][j][r] + bj);
    }

    // ---- in-register segmented product over the block's 64 rows ----
    // Thread (lane) holds rows {i*16 + g*4 + r} for its wave's 4 columns/j.
    // Run boundaries: lane r compares seg[m0+r] vs seg[m0+r-1] -> ballot mask.
    const int myseg  = seg[m0 + lane];                       // row 'lane'
    const int prevsg = (lane == 0) ? (myseg ^ 1) : seg[m0 + lane - 1];
    uint64_t m = __ballot(myseg != prevsg);                  // run-start bits

    while (m) {
        const int start = (int)__builtin_ctzll(m);
        m &= m - 1;
        const int end = m ? (int)__builtin_ctzll(m) : 64;
        const int s   = __shfl(myseg, start);                // run's segment id

        // predicated product over this thread's rows in [start, end)
        float p[4] = {1.0f, 1.0f, 1.0f, 1.0f};
        #pragma unroll
        for (int i = 0; i < 4; ++i)
            #pragma unroll
            for (int r = 0; r < 4; ++r) {
                const int row = i * 16 + g * 4 + r;
                const bool in = (row >= start) && (row < end);
                #pragma unroll
                for (int j = 0; j < 4; ++j)
                    p[j] *= in ? acc[i][j][r] : 1.0f;
            }
        // product across the 4 g-groups (lanes l16, l16+16, l16+32, l16+48)
        #pragma unroll
        for (int j = 0; j < 4; ++j) {
            p[j] *= __shfl_xor(p[j], 16);
            p[j] *= __shfl_xor(p[j], 32);
        }
        // g==0 lanes store this wave's 64 columns
        if (g == 0) {
            #pragma unroll
            for (int j = 0; j < 4; ++j) {
                const int col = n0 + j * 16 + l16;
                if (start == 0)
                    partial[(size_t)(bid * 2 + 0) * N_RANK + col] = p[j];
                else if (end == 64)
                    partial[(size_t)(bid * 2 + 1) * N_RANK + col] = p[j];
                else
                    out[(size_t)s * N_RANK + col] = p[j];    // interior: exclusive
            }
        }
    }
}

// Kernel 3 (pass 2): combine boundary partials. Block b owns boundary
// segment s iff s first appears in block b (seg[64b-1] < s). Owner multiplies
// its partial with forward blocks' P0 while seg[64*b2]==s, stores out[s].
// Interior segments were already stored by pass 1; empty segments stay 1.0.
__global__ void pass2_kernel(const int* __restrict__ seg,
                             const float* __restrict__ partial,
                             float* __restrict__ out) {
    const int b   = blockIdx.x;
    const int col = threadIdx.x;      // 0..255
    const int sF    = seg[b * 64];
    const int sL    = seg[b * 64 + 63];
    const int prevL = (b == 0) ? -1 : seg[b * 64 - 1];

    if (prevL < sF) {                 // b owns its first segment
        float p = partial[(size_t)(b * 2 + 0) * N_RANK + col];
        for (int b2 = b + 1; b2 < NB && seg[b2 * 64] == sF; ++b2)
            p *= partial[(size_t)(b2 * 2 + 0) * N_RANK + col];
        out[(size_t)sF * N_RANK + col] = p;
    }
    if (sL != sF) {                   // b always owns sL when sL != sF
        float p = partial[(size_t)(b * 2 + 1) * N_RANK + col];
        for (int b2 = b + 1; b2 < NB && seg[b2 * 64] == sL; ++b2)
            p *= partial[(size_t)(b2 * 2 + 0) * N_RANK + col];
        out[(size_t)sL * N_RANK + col] = p;
    }
}

extern "C" void kernel_launch(void* const* d_in, const int* in_sizes, int n_in,
                              void* d_out, int out_size, void* d_ws, size_t ws_size,
                              hipStream_t stream) {
    const float* x   = (const float*)d_in[0];
    const float* W   = (const float*)d_in[1];
    const float* b   = (const float*)d_in[2];
    const int*   seg = (const int*)d_in[3];
    float*       out = (float*)d_out;
    __hip_bfloat16* Wb = (__hip_bfloat16*)d_ws;                       // 256 KB
    float* partial = (float*)((char*)d_ws + (1 << 20));               // 4 MB @ +1MB

    prep_kernel<<<(NSEG * N_RANK) / 256, 256, 0, stream>>>(W, Wb, out);
    fused_kernel<<<NB, 256, 0, stream>>>(x, Wb, b, seg, out, partial);
    pass2_kernel<<<NB, 256, 0, stream>>>(seg, partial, out);
}

// Round 9
// 104.349 us; speedup vs baseline: 1.2658x; 1.0509x over previous
//
#include <hip/hip_runtime.h>
#include <hip/hip_bf16.h>
#include <stdint.h>

// Problem constants (from reference)
#define M_TOTAL 131072
#define K_DIM   512
#define N_RANK  256
#define NSEG    1024
#define KC      64            // k-chunk staged in LDS (64 f32 per row)
#define NKC     (K_DIM / KC)  // 8
#define NB      (M_TOTAL / 64)  // 2048 pass-1 blocks

typedef __attribute__((ext_vector_type(8))) short bf16x8;
typedef __attribute__((ext_vector_type(4))) float f32x4;

// Raw barrier: lgkmcnt(0) for LDS visibility, vmcnt NOT drained.
#define BAR() do { \
    asm volatile("s_waitcnt lgkmcnt(0)" ::: "memory"); \
    __builtin_amdgcn_s_barrier(); \
} while (0)

__device__ inline short f2b(float f) {
    __hip_bfloat16 h = __float2bfloat16(f);
    return __builtin_bit_cast(short, h);
}

// fast tanh: t = sign(z) * (1 - 2/(e^{2|z|}+1))
__device__ inline float fast_tanh(float z) {
    float e = __expf(2.0f * fabsf(z));
    return copysignf(1.0f - 2.0f / (e + 1.0f), z);
}

// Kernel 1: init out to 1.0 (segment_prod identity for empty segments)
//           + convert W to bf16 in ws
__global__ void prep_kernel(const float* __restrict__ W,
                            __hip_bfloat16* __restrict__ Wb,
                            float* __restrict__ out) {
    int i = blockIdx.x * 256 + threadIdx.x;
    out[i] = 1.0f;
    if (i < N_RANK * K_DIM) Wb[i] = __float2bfloat16(W[i]);
}

// Kernel 2 (pass 1): fused GEMM + bias + tanh + in-register segmented product.
//
// vmcnt-queue discipline (THE fix this round): vmcnt is an in-order counter.
// B-loads are issued BEFORE the next chunk's DMA, so B is OLDER than the
// prefetch. The compiler's wait before MFMA's B-use is then a counted
// vmcnt(4) that leaves DMA(kc+1) in flight across the compute phase and the
// barriers. (R6-R8 had DMA issued first -> B-use wait = vmcnt(0) -> the
// prefetch was drained EVERY iteration; ~900cy HBM latency serialized.)
// sched_barrier(0) pins stop the compiler sinking the pure B-loads back
// below the DMA (which would re-poison and invalidate the manual count).
__launch_bounds__(256, 3)
__global__ void fused_kernel(const float* __restrict__ x,
                             const __hip_bfloat16* __restrict__ Wb,
                             const float* __restrict__ bias,
                             const int* __restrict__ seg,
                             float* __restrict__ out,
                             float* __restrict__ partial) {
    const int tid  = threadIdx.x;
    const int wave = tid >> 6;
    const int lane = tid & 63;
    const int l16  = lane & 15;
    const int g    = lane >> 4;       // 0..3 (k-group / row-group)
    const int bid  = blockIdx.x;
    const int m0   = bid * 64;
    const int n0   = wave * 64;

    // LDS: A double-buffer only, 2 x (64 rows x 256B f32) = 32 KB.
    __shared__ alignas(16) char smem[32768];

    // ---- DMA geometry ----
    const int drow = lane >> 4;               // 0..3 row within 4-row slab
    const int dc16 = lane & 15;               // 16B slot within row

    f32x4 acc[4][4] = {};                     // [m-frag][n-frag]

    #define DMA_CHUNK(kc_, buf_)                                              \
        do {                                                                  \
            _Pragma("unroll")                                                 \
            for (int t = 0; t < 4; ++t) {                                     \
                const int r7   = (4 * t + drow) & 7;                          \
                const int cf   = ((dc16 ^ r7) << 2);  /* f32 col 0..63 */     \
                const float* gsrc = x + (size_t)(m0 + 16 * wave + 4 * t + drow) * K_DIM \
                                      + (kc_) * KC + cf;                      \
                uint32_t* ldst = reinterpret_cast<uint32_t*>(                 \
                    smem + (buf_) * 16384 + (wave * 4 + t) * 1024);           \
                __builtin_amdgcn_global_load_lds(                             \
                    reinterpret_cast<const uint32_t*>(gsrc), ldst, 16, 0, 0); \
            }                                                                 \
        } while (0)

    // ---- prologue: issue chunk 0 into buf 0 ----
    DMA_CHUNK(0, 0);

    // ---- K loop: 8 chunks of 64 ----
    #pragma unroll
    for (int kc = 0; kc < NKC; ++kc) {
        BAR();   // all waves done reading buf (kc+1)&1 (chunk kc-1) -> free

        // 1) B fragments FIRST (L2-resident). Older than the DMA below, so
        //    their consumption wait is counted and never drains the prefetch.
        bf16x8 bfr[2][4];
        #pragma unroll
        for (int s = 0; s < 2; ++s)
            #pragma unroll
            for (int j = 0; j < 4; ++j)
                bfr[s][j] = *reinterpret_cast<const bf16x8*>(
                    Wb + (size_t)(n0 + j * 16 + l16) * K_DIM + kc * KC + s * 32 + g * 8);
        __builtin_amdgcn_sched_barrier(0);   // pin: B-loads stay above the DMA

        // 2) issue DMA for chunk kc+1 (4 ops/wave, newest in queue)
        if (kc + 1 < NKC) DMA_CHUNK(kc + 1, (kc + 1) & 1);
        __builtin_amdgcn_sched_barrier(0);   // pin: DMA stays above the wait

        // 3) vmcnt(4): retires everything except the 4 newest (= DMA(kc+1)).
        //    Guarantees DMA(kc) landed (oldest); prefetch stays in flight.
        asm volatile("s_waitcnt vmcnt(4)" ::: "memory");
        BAR();   // whole A-buffer valid for every wave

        // 4) compute chunk kc from LDS buf kc&1
        const int bufb = (kc & 1) * 16384;
        #pragma unroll
        for (int s = 0; s < 2; ++s) {
            bf16x8 afr[4];
            #pragma unroll
            for (int i = 0; i < 4; ++i) {
                const int row = i * 16 + l16;
                const int X   = (l16 & 7) << 4;
                const int c0  = s * 128 + g * 32;
                f32x4 lo = *reinterpret_cast<const f32x4*>(smem + bufb + row * 256 + (c0 ^ X));
                f32x4 hi = *reinterpret_cast<const f32x4*>(smem + bufb + row * 256 + ((c0 + 16) ^ X));
                bf16x8 av;
                av[0] = f2b(lo[0]); av[1] = f2b(lo[1]);
                av[2] = f2b(lo[2]); av[3] = f2b(lo[3]);
                av[4] = f2b(hi[0]); av[5] = f2b(hi[1]);
                av[6] = f2b(hi[2]); av[7] = f2b(hi[3]);
                afr[i] = av;
            }
            #pragma unroll
            for (int i = 0; i < 4; ++i)
                #pragma unroll
                for (int j = 0; j < 4; ++j)
                    acc[i][j] = __builtin_amdgcn_mfma_f32_16x16x32_bf16(
                        afr[i], bfr[s][j], acc[i][j], 0, 0, 0);
        }
    }
    #undef DMA_CHUNK

    // ---- bias + tanh in regs ----
    // D layout: col = lane&15, row(within 16x16) = (lane>>4)*4 + r
    #pragma unroll
    for (int j = 0; j < 4; ++j) {
        const float bj = bias[n0 + j * 16 + l16];
        #pragma unroll
        for (int i = 0; i < 4; ++i)
            #pragma unroll
            for (int r = 0; r < 4; ++r)
                acc[i][j][r] = fast_tanh(acc[i][j][r] + bj);
    }

    // ---- in-register segmented product over the block's 64 rows ----
    const int myseg  = seg[m0 + lane];                       // row 'lane'
    const int prevsg = (lane == 0) ? (myseg ^ 1) : seg[m0 + lane - 1];
    uint64_t m = __ballot(myseg != prevsg);                  // run-start bits

    while (m) {
        const int start = (int)__builtin_ctzll(m);
        m &= m - 1;
        const int end = m ? (int)__builtin_ctzll(m) : 64;
        const int s   = __shfl(myseg, start);                // run's segment id

        float p[4] = {1.0f, 1.0f, 1.0f, 1.0f};
        #pragma unroll
        for (int i = 0; i < 4; ++i)
            #pragma unroll
            for (int r = 0; r < 4; ++r) {
                const int row = i * 16 + g * 4 + r;
                const bool in = (row >= start) && (row < end);
                #pragma unroll
                for (int j = 0; j < 4; ++j)
                    p[j] *= in ? acc[i][j][r] : 1.0f;
            }
        #pragma unroll
        for (int j = 0; j < 4; ++j) {
            p[j] *= __shfl_xor(p[j], 16);
            p[j] *= __shfl_xor(p[j], 32);
        }
        if (g == 0) {
            #pragma unroll
            for (int j = 0; j < 4; ++j) {
                const int col = n0 + j * 16 + l16;
                if (start == 0)
                    partial[(size_t)(bid * 2 + 0) * N_RANK + col] = p[j];
                else if (end == 64)
                    partial[(size_t)(bid * 2 + 1) * N_RANK + col] = p[j];
                else
                    out[(size_t)s * N_RANK + col] = p[j];    // interior: exclusive
            }
        }
    }
}

// Kernel 3 (pass 2): combine boundary partials. Block b owns boundary
// segment s iff s first appears in block b. Interior segments were stored
// by pass 1; empty segments stay 1.0.
__global__ void pass2_kernel(const int* __restrict__ seg,
                             const float* __restrict__ partial,
                             float* __restrict__ out) {
    const int b   = blockIdx.x;
    const int col = threadIdx.x;      // 0..255
    const int sF    = seg[b * 64];
    const int sL    = seg[b * 64 + 63];
    const int prevL = (b == 0) ? -1 : seg[b * 64 - 1];

    if (prevL < sF) {                 // b owns its first segment
        float p = partial[(size_t)(b * 2 + 0) * N_RANK + col];
        for (int b2 = b + 1; b2 < NB && seg[b2 * 64] == sF; ++b2)
            p *= partial[(size_t)(b2 * 2 + 0) * N_RANK + col];
        out[(size_t)sF * N_RANK + col] = p;
    }
    if (sL != sF) {                   // b always owns sL when sL != sF
        float p = partial[(size_t)(b * 2 + 1) * N_RANK + col];
        for (int b2 = b + 1; b2 < NB && seg[b2 * 64] == sL; ++b2)
            p *= partial[(size_t)(b2 * 2 + 0) * N_RANK + col];
        out[(size_t)sL * N_RANK + col] = p;
    }
}

extern "C" void kernel_launch(void* const* d_in, const int* in_sizes, int n_in,
                              void* d_out, int out_size, void* d_ws, size_t ws_size,
                              hipStream_t stream) {
    const float* x   = (const float*)d_in[0];
    const float* W   = (const float*)d_in[1];
    const float* b   = (const float*)d_in[2];
    const int*   seg = (const int*)d_in[3];
    float*       out = (float*)d_out;
    __hip_bfloat16* Wb = (__hip_bfloat16*)d_ws;                       // 256 KB
    float* partial = (float*)((char*)d_ws + (1 << 20));               // 4 MB @ +1MB

    prep_kernel<<<(NSEG * N_RANK) / 256, 256, 0, stream>>>(W, Wb, out);
    fused_kernel<<<NB, 256, 0, stream>>>(x, Wb, b, seg, out, partial);
    pass2_kernel<<<NB, 256, 0, stream>>>(seg, partial, out);
}

// Round 10
// 95.510 us; speedup vs baseline: 1.3829x; 1.0925x over previous
//
#include <hip/hip_runtime.h>
#include <hip/hip_bf16.h>
#include <stdint.h>

// Problem constants (from reference)
#define M_TOTAL 131072
#define K_DIM   512
#define N_RANK  256
#define NSEG    1024
#define KC      64              // k-chunk staged in LDS (64 f32 per row)
#define NKC     (K_DIM / KC)    // 8
#define BM      128             // rows per block (was 64)
#define NBLK    (M_TOTAL / BM)  // 1024 fused blocks
#define NB64    (M_TOTAL / 64)  // 2048 virtual 64-row groups (pass2 granularity)

typedef __attribute__((ext_vector_type(8))) short bf16x8;
typedef __attribute__((ext_vector_type(4))) float f32x4;

// Raw barrier: lgkmcnt(0) for LDS visibility, vmcnt NOT drained.
#define BAR() do { \
    asm volatile("s_waitcnt lgkmcnt(0)" ::: "memory"); \
    __builtin_amdgcn_s_barrier(); \
} while (0)

__device__ inline short f2b(float f) {
    __hip_bfloat16 h = __float2bfloat16(f);
    return __builtin_bit_cast(short, h);
}

// fast tanh: t = sign(z) * (1 - 2/(e^{2|z|}+1))
__device__ inline float fast_tanh(float z) {
    float e = __expf(2.0f * fabsf(z));
    return copysignf(1.0f - 2.0f / (e + 1.0f), z);
}

// Kernel 1: init out to 1.0 (segment_prod identity for empty segments)
//           + convert W to bf16 in ws
__global__ void prep_kernel(const float* __restrict__ W,
                            __hip_bfloat16* __restrict__ Wb,
                            float* __restrict__ out) {
    int i = blockIdx.x * 256 + threadIdx.x;
    out[i] = 1.0f;
    if (i < N_RANK * K_DIM) Wb[i] = __float2bfloat16(W[i]);
}

// Kernel 2 (pass 1): fused GEMM + bias + tanh + in-register segmented product.
//
// R10 restructure: 128-row tile, 512 threads = 8 waves, 1024 blocks.
// Waves are COLUMN-slices: wave w owns cols [w*32, w*32+32) x all 128 rows
// (acc[8][2]). vs R9: B-loads/wave/chunk 8->4 with no duplication (total B
// traffic 512->256 MB), chunk-instances 16384->8192, 2 blocks/CU (64 KB LDS
// dbuf) = 16 waves/CU, MFMA per barrier-pair per CU 384->512.
//
// vmcnt-queue discipline (from R9): B-loads issued BEFORE the next chunk's
// DMA -> B is older; manual vmcnt(4) retires B(kc)+DMA(kc) but leaves
// DMA(kc+1) in flight across compute + barriers. sched_barrier(0) pins stop
// the compiler reordering pure loads across the DMA.
__launch_bounds__(512, 4)   // VGPR cap 128; spill canary = WRITE_SIZE balloon
__global__ void fused_kernel(const float* __restrict__ x,
                             const __hip_bfloat16* __restrict__ Wb,
                             const float* __restrict__ bias,
                             const int* __restrict__ seg,
                             float* __restrict__ out,
                             float* __restrict__ partial) {
    const int tid  = threadIdx.x;
    const int wave = tid >> 6;        // 0..7 = column-slice
    const int lane = tid & 63;
    const int l16  = lane & 15;
    const int g    = lane >> 4;       // 0..3 (k-group / row-group)
    const int bid  = blockIdx.x;
    const int m0   = bid * BM;
    const int n0   = wave * 32;

    // LDS: A double-buffer, 2 x (128 rows x 256B f32) = 64 KB.
    __shared__ alignas(16) char smem[65536];

    // ---- DMA geometry: wave stages rows 16*wave .. 16*wave+15 ----
    const int drow = lane >> 4;               // 0..3 row within 4-row slab
    const int dc16 = lane & 15;               // 16B slot within row

    f32x4 acc[8][2] = {};                     // [m-frag][n-frag]

    #define DMA_CHUNK(kc_, buf_)                                              \
        do {                                                                  \
            _Pragma("unroll")                                                 \
            for (int t = 0; t < 4; ++t) {                                     \
                const int r7   = (4 * t + drow) & 7;                          \
                const int cf   = ((dc16 ^ r7) << 2);  /* f32 col 0..63 */     \
                const float* gsrc = x + (size_t)(m0 + 16 * wave + 4 * t + drow) * K_DIM \
                                      + (kc_) * KC + cf;                      \
                uint32_t* ldst = reinterpret_cast<uint32_t*>(                 \
                    smem + (buf_) * 32768 + (wave * 4 + t) * 1024);           \
                __builtin_amdgcn_global_load_lds(                             \
                    reinterpret_cast<const uint32_t*>(gsrc), ldst, 16, 0, 0); \
            }                                                                 \
        } while (0)

    // ---- prologue: issue chunk 0 into buf 0 ----
    DMA_CHUNK(0, 0);

    // ---- K loop: 8 chunks of 64 ----
    #pragma unroll
    for (int kc = 0; kc < NKC; ++kc) {
        BAR();   // all waves done reading buf (kc+1)&1 (chunk kc-1) -> free

        // 1) B fragments FIRST (L2-resident, 4 loads/wave). Older than the
        //    DMA below -> their consumption wait never drains the prefetch.
        bf16x8 bfr[2][2];
        #pragma unroll
        for (int s = 0; s < 2; ++s)
            #pragma unroll
            for (int j = 0; j < 2; ++j)
                bfr[s][j] = *reinterpret_cast<const bf16x8*>(
                    Wb + (size_t)(n0 + j * 16 + l16) * K_DIM + kc * KC + s * 32 + g * 8);
        __builtin_amdgcn_sched_barrier(0);   // pin: B-loads stay above the DMA

        // 2) issue DMA for chunk kc+1 (4 ops/wave, newest in queue)
        if (kc + 1 < NKC) DMA_CHUNK(kc + 1, (kc + 1) & 1);
        __builtin_amdgcn_sched_barrier(0);   // pin: DMA stays above the wait

        // 3) vmcnt(4): retires all but the 4 newest (= DMA(kc+1)).
        //    Guarantees DMA(kc) landed (oldest) and B(kc) in regs.
        asm volatile("s_waitcnt vmcnt(4)" ::: "memory");
        BAR();   // whole A-buffer valid for every wave

        // 4) compute chunk kc from LDS buf kc&1
        const int bufb = (kc & 1) * 32768;
        #pragma unroll
        for (int s = 0; s < 2; ++s) {
            #pragma unroll
            for (int i = 0; i < 8; ++i) {
                const int row = i * 16 + l16;
                const int X   = (l16 & 7) << 4;
                const int c0  = s * 128 + g * 32;
                f32x4 lo = *reinterpret_cast<const f32x4*>(smem + bufb + row * 256 + (c0 ^ X));
                f32x4 hi = *reinterpret_cast<const f32x4*>(smem + bufb + row * 256 + ((c0 + 16) ^ X));
                bf16x8 av;
                av[0] = f2b(lo[0]); av[1] = f2b(lo[1]);
                av[2] = f2b(lo[2]); av[3] = f2b(lo[3]);
                av[4] = f2b(hi[0]); av[5] = f2b(hi[1]);
                av[6] = f2b(hi[2]); av[7] = f2b(hi[3]);
                #pragma unroll
                for (int j = 0; j < 2; ++j)
                    acc[i][j] = __builtin_amdgcn_mfma_f32_16x16x32_bf16(
                        av, bfr[s][j], acc[i][j], 0, 0, 0);
            }
        }
    }
    #undef DMA_CHUNK

    // ---- bias + tanh in regs ----
    // D layout: col = lane&15, row(within 16x16) = (lane>>4)*4 + r
    #pragma unroll
    for (int j = 0; j < 2; ++j) {
        const float bj = bias[n0 + j * 16 + l16];
        #pragma unroll
        for (int i = 0; i < 8; ++i)
            #pragma unroll
            for (int r = 0; r < 4; ++r)
                acc[i][j][r] = fast_tanh(acc[i][j][r] + bj);
    }

    // ---- in-register segmented product, per 64-row half h ----
    // Virtual 64-row group vb = bid*2 + h keeps partial/pass2 identical to R9.
    #pragma unroll
    for (int h = 0; h < 2; ++h) {
        const int vb     = bid * 2 + h;
        const int myseg  = seg[m0 + h * 64 + lane];
        const int prevsg = (lane == 0) ? (myseg ^ 1) : seg[m0 + h * 64 + lane - 1];
        uint64_t m = __ballot(myseg != prevsg);              // run-start bits

        while (m) {
            const int start = (int)__builtin_ctzll(m);
            m &= m - 1;
            const int end = m ? (int)__builtin_ctzll(m) : 64;
            const int s   = __shfl(myseg, start);            // run's segment id

            float p[2] = {1.0f, 1.0f};
            #pragma unroll
            for (int i2 = 0; i2 < 4; ++i2)
                #pragma unroll
                for (int r = 0; r < 4; ++r) {
                    const int row = i2 * 16 + g * 4 + r;     // row within half
                    const bool in = (row >= start) && (row < end);
                    #pragma unroll
                    for (int j = 0; j < 2; ++j)
                        p[j] *= in ? acc[h * 4 + i2][j][r] : 1.0f;
                }
            #pragma unroll
            for (int j = 0; j < 2; ++j) {
                p[j] *= __shfl_xor(p[j], 16);
                p[j] *= __shfl_xor(p[j], 32);
            }
            if (g == 0) {
                #pragma unroll
                for (int j = 0; j < 2; ++j) {
                    const int col = n0 + j * 16 + l16;
                    if (start == 0)
                        partial[(size_t)(vb * 2 + 0) * N_RANK + col] = p[j];
                    else if (end == 64)
                        partial[(size_t)(vb * 2 + 1) * N_RANK + col] = p[j];
                    else
                        out[(size_t)s * N_RANK + col] = p[j]; // interior: exclusive
                }
            }
        }
    }
}

// Kernel 3 (pass 2): combine boundary partials over 64-row groups (b = vb).
// Group b owns boundary segment s iff s first appears in group b. Interior
// segments were stored by pass 1; empty segments stay 1.0.
__global__ void pass2_kernel(const int* __restrict__ seg,
                             const float* __restrict__ partial,
                             float* __restrict__ out) {
    const int b   = blockIdx.x;
    const int col = threadIdx.x;      // 0..255
    const int sF    = seg[b * 64];
    const int sL    = seg[b * 64 + 63];
    const int prevL = (b == 0) ? -1 : seg[b * 64 - 1];

    if (prevL < sF) {                 // b owns its first segment
        float p = partial[(size_t)(b * 2 + 0) * N_RANK + col];
        for (int b2 = b + 1; b2 < NB64 && seg[b2 * 64] == sF; ++b2)
            p *= partial[(size_t)(b2 * 2 + 0) * N_RANK + col];
        out[(size_t)sF * N_RANK + col] = p;
    }
    if (sL != sF) {                   // b always owns sL when sL != sF
        float p = partial[(size_t)(b * 2 + 1) * N_RANK + col];
        for (int b2 = b + 1; b2 < NB64 && seg[b2 * 64] == sL; ++b2)
            p *= partial[(size_t)(b2 * 2 + 0) * N_RANK + col];
        out[(size_t)sL * N_RANK + col] = p;
    }
}

extern "C" void kernel_launch(void* const* d_in, const int* in_sizes, int n_in,
                              void* d_out, int out_size, void* d_ws, size_t ws_size,
                              hipStream_t stream) {
    const float* x   = (const float*)d_in[0];
    const float* W   = (const float*)d_in[1];
    const float* b   = (const float*)d_in[2];
    const int*   seg = (const int*)d_in[3];
    float*       out = (float*)d_out;
    __hip_bfloat16* Wb = (__hip_bfloat16*)d_ws;                       // 256 KB
    float* partial = (float*)((char*)d_ws + (1 << 20));               // 4 MB @ +1MB

    prep_kernel<<<(NSEG * N_RANK) / 256, 256, 0, stream>>>(W, Wb, out);
    fused_kernel<<<NBLK, 512, 0, stream>>>(x, Wb, b, seg, out, partial);
    pass2_kernel<<<NB64, 256, 0, stream>>>(seg, partial, out);
}

// Round 11
// 88.845 us; speedup vs baseline: 1.4867x; 1.0750x over previous
//
#include <hip/hip_runtime.h>
#include <hip/hip_bf16.h>
#include <stdint.h>

// Problem constants (from reference)
#define M_TOTAL 131072
#define K_DIM   512
#define N_RANK  256
#define NSEG    1024
#define KC      64              // k-chunk staged in LDS (64 f32 per row)
#define NKC     (K_DIM / KC)    // 8
#define BM      128             // rows per block
#define NBLK    (M_TOTAL / BM)  // 1024 fused blocks
#define NB64    (M_TOTAL / 64)  // 2048 virtual 64-row groups (pass2 granularity)

typedef __attribute__((ext_vector_type(8))) short bf16x8;
typedef __attribute__((ext_vector_type(4))) float f32x4;

__device__ inline short f2b(float f) {
    __hip_bfloat16 h = __float2bfloat16(f);
    return __builtin_bit_cast(short, h);
}

// fast tanh: t = sign(z) * (1 - 2/(e^{2|z|}+1))
__device__ inline float fast_tanh(float z) {
    float e = __expf(2.0f * fabsf(z));
    return copysignf(1.0f - 2.0f / (e + 1.0f), z);
}

// Kernel 1: init out to 1.0 (segment_prod identity for empty segments)
//           + convert W to bf16 in ws
__global__ void prep_kernel(const float* __restrict__ W,
                            __hip_bfloat16* __restrict__ Wb,
                            float* __restrict__ out) {
    int i = blockIdx.x * 256 + threadIdx.x;
    out[i] = 1.0f;
    if (i < N_RANK * K_DIM) Wb[i] = __float2bfloat16(W[i]);
}

// Kernel 2 (pass 1): fused GEMM + bias + tanh + in-register segmented product.
//
// R11: single-barrier 2-phase K-loop (guide T3 minimum skeleton).
//   iter kc: vmcnt(0)  -- own DMA(kc) landed; nothing else outstanding
//            s_barrier -- all waves' DMA(kc) landed AND all reads of
//                         buf[(kc+1)&1] (chunk kc-1) retired (program order)
//            B(kc) loads (older in queue than the DMA below -> the compiler's
//                         B-use wait is vmcnt(4), leaving the prefetch in flight)
//            DMA(kc+1) -> buf[(kc+1)&1]   (flies across the whole compute)
//            compute chunk kc from buf[kc&1]
// vs R10: one rendezvous per chunk instead of two, no lgkmcnt (loop has no
// ds_writes; DMA completion is vmcnt), same queue discipline as R9/R10.
__launch_bounds__(512, 4)   // VGPR cap 128; spill canary = WRITE_SIZE balloon
__global__ void fused_kernel(const float* __restrict__ x,
                             const __hip_bfloat16* __restrict__ Wb,
                             const float* __restrict__ bias,
                             const int* __restrict__ seg,
                             float* __restrict__ out,
                             float* __restrict__ partial) {
    const int tid  = threadIdx.x;
    const int wave = tid >> 6;        // 0..7 = column-slice
    const int lane = tid & 63;
    const int l16  = lane & 15;
    const int g    = lane >> 4;       // 0..3 (k-group / row-group)
    const int bid  = blockIdx.x;
    const int m0   = bid * BM;
    const int n0   = wave * 32;

    // LDS: A double-buffer, 2 x (128 rows x 256B f32) = 64 KB.
    __shared__ alignas(16) char smem[65536];

    // ---- DMA geometry: wave stages rows 16*wave .. 16*wave+15 ----
    const int drow = lane >> 4;               // 0..3 row within 4-row slab
    const int dc16 = lane & 15;               // 16B slot within row

    f32x4 acc[8][2] = {};                     // [m-frag][n-frag]

    #define DMA_CHUNK(kc_, buf_)                                              \
        do {                                                                  \
            _Pragma("unroll")                                                 \
            for (int t = 0; t < 4; ++t) {                                     \
                const int r7   = (4 * t + drow) & 7;                          \
                const int cf   = ((dc16 ^ r7) << 2);  /* f32 col 0..63 */     \
                const float* gsrc = x + (size_t)(m0 + 16 * wave + 4 * t + drow) * K_DIM \
                                      + (kc_) * KC + cf;                      \
                uint32_t* ldst = reinterpret_cast<uint32_t*>(                 \
                    smem + (buf_) * 32768 + (wave * 4 + t) * 1024);           \
                __builtin_amdgcn_global_load_lds(                             \
                    reinterpret_cast<const uint32_t*>(gsrc), ldst, 16, 0, 0); \
            }                                                                 \
        } while (0)

    // ---- prologue: issue chunk 0 into buf 0 ----
    DMA_CHUNK(0, 0);

    // ---- K loop: 8 chunks of 64, ONE barrier per chunk ----
    #pragma unroll
    for (int kc = 0; kc < NKC; ++kc) {
        // own DMA(kc) landed (only outstanding VMEM at this point)
        asm volatile("s_waitcnt vmcnt(0)" ::: "memory");
        // all waves landed their DMA(kc); all reads of buf[(kc+1)&1] retired
        __builtin_amdgcn_s_barrier();

        // 1) B fragments (L2-resident, 4 loads/wave) -- issued BEFORE the DMA
        //    so their consumption wait never drains the prefetch.
        bf16x8 bfr[2][2];
        #pragma unroll
        for (int s = 0; s < 2; ++s)
            #pragma unroll
            for (int j = 0; j < 2; ++j)
                bfr[s][j] = *reinterpret_cast<const bf16x8*>(
                    Wb + (size_t)(n0 + j * 16 + l16) * K_DIM + kc * KC + s * 32 + g * 8);
        __builtin_amdgcn_sched_barrier(0);   // pin: B-loads stay above the DMA

        // 2) issue DMA for chunk kc+1 (newest in queue; flies across compute)
        if (kc + 1 < NKC) DMA_CHUNK(kc + 1, (kc + 1) & 1);
        __builtin_amdgcn_sched_barrier(0);   // pin: DMA stays above compute

        // 3) compute chunk kc from LDS buf kc&1 (compiler emits vmcnt(4)
        //    before the first B use -> DMA(kc+1) stays in flight)
        const int bufb = (kc & 1) * 32768;
        #pragma unroll
        for (int s = 0; s < 2; ++s) {
            #pragma unroll
            for (int i = 0; i < 8; ++i) {
                const int row = i * 16 + l16;
                const int X   = (l16 & 7) << 4;
                const int c0  = s * 128 + g * 32;
                f32x4 lo = *reinterpret_cast<const f32x4*>(smem + bufb + row * 256 + (c0 ^ X));
                f32x4 hi = *reinterpret_cast<const f32x4*>(smem + bufb + row * 256 + ((c0 + 16) ^ X));
                bf16x8 av;
                av[0] = f2b(lo[0]); av[1] = f2b(lo[1]);
                av[2] = f2b(lo[2]); av[3] = f2b(lo[3]);
                av[4] = f2b(hi[0]); av[5] = f2b(hi[1]);
                av[6] = f2b(hi[2]); av[7] = f2b(hi[3]);
                #pragma unroll
                for (int j = 0; j < 2; ++j)
                    acc[i][j] = __builtin_amdgcn_mfma_f32_16x16x32_bf16(
                        av, bfr[s][j], acc[i][j], 0, 0, 0);
            }
        }
    }
    #undef DMA_CHUNK

    // ---- bias + tanh in regs ----
    // D layout: col = lane&15, row(within 16x16) = (lane>>4)*4 + r
    #pragma unroll
    for (int j = 0; j < 2; ++j) {
        const float bj = bias[n0 + j * 16 + l16];
        #pragma unroll
        for (int i = 0; i < 8; ++i)
            #pragma unroll
            for (int r = 0; r < 4; ++r)
                acc[i][j][r] = fast_tanh(acc[i][j][r] + bj);
    }

    // ---- in-register segmented product, per 64-row half h ----
    // Virtual 64-row group vb = bid*2 + h keeps partial/pass2 layout stable.
    #pragma unroll
    for (int h = 0; h < 2; ++h) {
        const int vb     = bid * 2 + h;
        const int myseg  = seg[m0 + h * 64 + lane];
        const int prevsg = (lane == 0) ? (myseg ^ 1) : seg[m0 + h * 64 + lane - 1];
        uint64_t m = __ballot(myseg != prevsg);              // run-start bits

        while (m) {
            const int start = (int)__builtin_ctzll(m);
            m &= m - 1;
            const int end = m ? (int)__builtin_ctzll(m) : 64;
            const int s   = __shfl(myseg, start);            // run's segment id

            float p[2] = {1.0f, 1.0f};
            #pragma unroll
            for (int i2 = 0; i2 < 4; ++i2)
                #pragma unroll
                for (int r = 0; r < 4; ++r) {
                    const int row = i2 * 16 + g * 4 + r;     // row within half
                    const bool in = (row >= start) && (row < end);
                    #pragma unroll
                    for (int j = 0; j < 2; ++j)
                        p[j] *= in ? acc[h * 4 + i2][j][r] : 1.0f;
                }
            #pragma unroll
            for (int j = 0; j < 2; ++j) {
                p[j] *= __shfl_xor(p[j], 16);
                p[j] *= __shfl_xor(p[j], 32);
            }
            if (g == 0) {
                #pragma unroll
                for (int j = 0; j < 2; ++j) {
                    const int col = n0 + j * 16 + l16;
                    if (start == 0)
                        partial[(size_t)(vb * 2 + 0) * N_RANK + col] = p[j];
                    else if (end == 64)
                        partial[(size_t)(vb * 2 + 1) * N_RANK + col] = p[j];
                    else
                        out[(size_t)s * N_RANK + col] = p[j]; // interior: exclusive
                }
            }
        }
    }
}

// Kernel 3 (pass 2): combine boundary partials over 64-row groups (b = vb).
// Group b owns boundary segment s iff s first appears in group b. Interior
// segments were stored by pass 1; empty segments stay 1.0.
__global__ void pass2_kernel(const int* __restrict__ seg,
                             const float* __restrict__ partial,
                             float* __restrict__ out) {
    const int b   = blockIdx.x;
    const int col = threadIdx.x;      // 0..255
    const int sF    = seg[b * 64];
    const int sL    = seg[b * 64 + 63];
    const int prevL = (b == 0) ? -1 : seg[b * 64 - 1];

    if (prevL < sF) {                 // b owns its first segment
        float p = partial[(size_t)(b * 2 + 0) * N_RANK + col];
        for (int b2 = b + 1; b2 < NB64 && seg[b2 * 64] == sF; ++b2)
            p *= partial[(size_t)(b2 * 2 + 0) * N_RANK + col];
        out[(size_t)sF * N_RANK + col] = p;
    }
    if (sL != sF) {                   // b always owns sL when sL != sF
        float p = partial[(size_t)(b * 2 + 1) * N_RANK + col];
        for (int b2 = b + 1; b2 < NB64 && seg[b2 * 64] == sL; ++b2)
            p *= partial[(size_t)(b2 * 2 + 0) * N_RANK + col];
        out[(size_t)sL * N_RANK + col] = p;
    }
}

extern "C" void kernel_launch(void* const* d_in, const int* in_sizes, int n_in,
                              void* d_out, int out_size, void* d_ws, size_t ws_size,
                              hipStream_t stream) {
    const float* x   = (const float*)d_in[0];
    const float* W   = (const float*)d_in[1];
    const float* b   = (const float*)d_in[2];
    const int*   seg = (const int*)d_in[3];
    float*       out = (float*)d_out;
    __hip_bfloat16* Wb = (__hip_bfloat16*)d_ws;                       // 256 KB
    float* partial = (float*)((char*)d_ws + (1 << 20));               // 4 MB @ +1MB

    prep_kernel<<<(NSEG * N_RANK) / 256, 256, 0, stream>>>(W, Wb, out);
    fused_kernel<<<NBLK, 512, 0, stream>>>(x, Wb, b, seg, out, partial);
    pass2_kernel<<<NB64, 256, 0, stream>>>(seg, partial, out);
}

// Round 12
// 81.386 us; speedup vs baseline: 1.6230x; 1.0917x over previous
//
#include <hip/hip_runtime.h>
#include <hip/hip_bf16.h>
#include <stdint.h>

// Problem constants (from reference)
#define M_TOTAL 131072
#define K_DIM   512
#define N_RANK  256
#define NSEG    1024
#define KC      64              // k-chunk staged in LDS (64 bf16 per row)
#define NKC     (K_DIM / KC)    // 8
#define BM      128             // rows per block
#define NBLK    (M_TOTAL / BM)  // 1024 fused blocks
#define NB64    (M_TOTAL / 64)  // 2048 virtual 64-row groups (pass2 granularity)

typedef __attribute__((ext_vector_type(8))) short bf16x8;
typedef __attribute__((ext_vector_type(4))) float f32x4;

// Raw barrier: lgkmcnt(0) makes my ds_writes visible, vmcnt NOT drained.
#define BAR() do { \
    asm volatile("s_waitcnt lgkmcnt(0)" ::: "memory"); \
    __builtin_amdgcn_s_barrier(); \
} while (0)

__device__ inline short f2b(float f) {
    __hip_bfloat16 h = __float2bfloat16(f);
    return __builtin_bit_cast(short, h);
}

// fast tanh: t = sign(z) * (1 - 2/(e^{2|z|}+1))
__device__ inline float fast_tanh(float z) {
    float e = __expf(2.0f * fabsf(z));
    return copysignf(1.0f - 2.0f / (e + 1.0f), z);
}

// Kernel 1: init out to 1.0 (segment_prod identity for empty segments)
//           + convert W to bf16 in ws
__global__ void prep_kernel(const float* __restrict__ W,
                            __hip_bfloat16* __restrict__ Wb,
                            float* __restrict__ out) {
    int i = blockIdx.x * 256 + threadIdx.x;
    out[i] = 1.0f;
    if (i < N_RANK * K_DIM) Wb[i] = __float2bfloat16(W[i]);
}

// Kernel 2 (pass 1): fused GEMM + bias + tanh + in-register segmented product.
//
// R12: A staged in LDS as BF16, converted ONCE at stage-write time.
// (R11 staged f32 and converted at read time -> every wave converted the
// same chunk = 8x redundant VALU on the ds_read->MFMA critical path.)
// MFMA A-fragment = one ds_read_b128, zero VALU between LDS and MFMA.
//
// T14 async-STAGE split per iter kc (single barrier, queue discipline R9):
//   BAR (lgkmcnt0+barrier): buf[kc&1] written+visible; buf[(kc+1)&1] free
//   B(kc) loads            (oldest VMEM -> B-use wait = counted vmcnt(4))
//   G(kc+1) f32x4 loads    (newest; fly across the whole compute phase)
//   compute(kc): 16 ds_read_b128 + 32 MFMA per wave
//   vmcnt(0); cvt; 4x ds_write_b64 -> buf[(kc+1)&1]
__launch_bounds__(512, 4)   // VGPR cap 128; spill canary = WRITE_SIZE balloon
__global__ void fused_kernel(const float* __restrict__ x,
                             const __hip_bfloat16* __restrict__ Wb,
                             const float* __restrict__ bias,
                             const int* __restrict__ seg,
                             float* __restrict__ out,
                             float* __restrict__ partial) {
    const int tid  = threadIdx.x;
    const int wave = tid >> 6;        // 0..7 = column-slice
    const int lane = tid & 63;
    const int l16  = lane & 15;
    const int g    = lane >> 4;       // 0..3 (k-group / row-group)
    const int bid  = blockIdx.x;
    const int m0   = bid * BM;
    const int n0   = wave * 32;

    // LDS: A double-buffer, 2 x (128 rows x 128B bf16) = 32 KB.
    __shared__ alignas(16) char smem[32768];

    // ---- staging geometry: thread covers one 16B f32 slot, 4 slabs ----
    // slab it (0..3): row = it*32 + (tid>>4), f32 col = (tid&15)*4
    const int srow = tid >> 4;        // 0..31
    const int sc16 = tid & 15;

    f32x4 acc[8][2] = {};             // [m-frag][n-frag]
    f32x4 sg[4];                      // staged f32 for next chunk

    #define STAGE_LOAD(kc_)                                                   \
        do {                                                                  \
            _Pragma("unroll")                                                 \
            for (int it = 0; it < 4; ++it)                                    \
                sg[it] = *reinterpret_cast<const f32x4*>(                     \
                    x + (size_t)(m0 + it * 32 + srow) * K_DIM + (kc_) * KC + sc16 * 4); \
        } while (0)

    // write 4 bf16 (8B) per slab; XOR-swizzle at 16B granularity (bit3 kept)
    #define STAGE_WRITE(buf_)                                                 \
        do {                                                                  \
            _Pragma("unroll")                                                 \
            for (int it = 0; it < 4; ++it) {                                  \
                const int row = it * 32 + srow;                               \
                short4 p;                                                     \
                p.x = f2b(sg[it][0]); p.y = f2b(sg[it][1]);                   \
                p.z = f2b(sg[it][2]); p.w = f2b(sg[it][3]);                   \
                *reinterpret_cast<short4*>(smem + (buf_) * 16384 + row * 128  \
                    + ((sc16 * 8) ^ ((row & 7) << 4))) = p;                   \
            }                                                                 \
        } while (0)

    // ---- prologue: stage chunk 0 into buf 0 ----
    STAGE_LOAD(0);
    asm volatile("s_waitcnt vmcnt(0)" ::: "memory");
    STAGE_WRITE(0);

    // ---- K loop: 8 chunks of 64, ONE barrier per chunk ----
    #pragma unroll
    for (int kc = 0; kc < NKC; ++kc) {
        BAR();   // buf[kc&1] visible to all; buf[(kc+1)&1] free to write

        // 1) B fragments (L2-resident, 4 loads/wave) -- oldest in VMEM queue
        bf16x8 bfr[2][2];
        #pragma unroll
        for (int s = 0; s < 2; ++s)
            #pragma unroll
            for (int j = 0; j < 2; ++j)
                bfr[s][j] = *reinterpret_cast<const bf16x8*>(
                    Wb + (size_t)(n0 + j * 16 + l16) * K_DIM + kc * KC + s * 32 + g * 8);
        __builtin_amdgcn_sched_barrier(0);   // pin: B-loads stay above G-loads

        // 2) issue G loads for chunk kc+1 (newest; fly across compute)
        if (kc + 1 < NKC) STAGE_LOAD(kc + 1);
        __builtin_amdgcn_sched_barrier(0);   // pin: G-loads stay above compute

        // 3) compute chunk kc from LDS buf kc&1 (A-frag = 1 ds_read_b128;
        //    compiler's B-use wait = vmcnt(4), G stays in flight)
        const int bufb = (kc & 1) * 16384;
        #pragma unroll
        for (int s = 0; s < 2; ++s) {
            #pragma unroll
            for (int i = 0; i < 8; ++i) {
                const int row = i * 16 + l16;
                bf16x8 av = *reinterpret_cast<const bf16x8*>(
                    smem + bufb + row * 128 + ((s * 64 + g * 16) ^ ((row & 7) << 4)));
                #pragma unroll
                for (int j = 0; j < 2; ++j)
                    acc[i][j] = __builtin_amdgcn_mfma_f32_16x16x32_bf16(
                        av, bfr[s][j], acc[i][j], 0, 0, 0);
            }
        }

        // 4) convert + write the prefetched chunk (loads had whole compute)
        if (kc + 1 < NKC) {
            asm volatile("s_waitcnt vmcnt(0)" ::: "memory");
            STAGE_WRITE((kc + 1) & 1);
        }
    }
    #undef STAGE_LOAD
    #undef STAGE_WRITE

    // ---- bias + tanh in regs ----
    // D layout: col = lane&15, row(within 16x16) = (lane>>4)*4 + r
    #pragma unroll
    for (int j = 0; j < 2; ++j) {
        const float bj = bias[n0 + j * 16 + l16];
        #pragma unroll
        for (int i = 0; i < 8; ++i)
            #pragma unroll
            for (int r = 0; r < 4; ++r)
                acc[i][j][r] = fast_tanh(acc[i][j][r] + bj);
    }

    // ---- in-register segmented product, per 64-row half h ----
    // Virtual 64-row group vb = bid*2 + h keeps partial/pass2 layout stable.
    #pragma unroll
    for (int h = 0; h < 2; ++h) {
        const int vb     = bid * 2 + h;
        const int myseg  = seg[m0 + h * 64 + lane];
        const int prevsg = (lane == 0) ? (myseg ^ 1) : seg[m0 + h * 64 + lane - 1];
        uint64_t m = __ballot(myseg != prevsg);              // run-start bits

        while (m) {
            const int start = (int)__builtin_ctzll(m);
            m &= m - 1;
            const int end = m ? (int)__builtin_ctzll(m) : 64;
            const int s   = __shfl(myseg, start);            // run's segment id

            float p[2] = {1.0f, 1.0f};
            #pragma unroll
            for (int i2 = 0; i2 < 4; ++i2)
                #pragma unroll
                for (int r = 0; r < 4; ++r) {
                    const int row = i2 * 16 + g * 4 + r;     // row within half
                    const bool in = (row >= start) && (row < end);
                    #pragma unroll
                    for (int j = 0; j < 2; ++j)
                        p[j] *= in ? acc[h * 4 + i2][j][r] : 1.0f;
                }
            #pragma unroll
            for (int j = 0; j < 2; ++j) {
                p[j] *= __shfl_xor(p[j], 16);
                p[j] *= __shfl_xor(p[j], 32);
            }
            if (g == 0) {
                #pragma unroll
                for (int j = 0; j < 2; ++j) {
                    const int col = n0 + j * 16 + l16;
                    if (start == 0)
                        partial[(size_t)(vb * 2 + 0) * N_RANK + col] = p[j];
                    else if (end == 64)
                        partial[(size_t)(vb * 2 + 1) * N_RANK + col] = p[j];
                    else
                        out[(size_t)s * N_RANK + col] = p[j]; // interior: exclusive
                }
            }
        }
    }
}

// Kernel 3 (pass 2): combine boundary partials over 64-row groups (b = vb).
// Group b owns boundary segment s iff s first appears in group b. Interior
// segments were stored by pass 1; empty segments stay 1.0.
__global__ void pass2_kernel(const int* __restrict__ seg,
                             const float* __restrict__ partial,
                             float* __restrict__ out) {
    const int b   = blockIdx.x;
    const int col = threadIdx.x;      // 0..255
    const int sF    = seg[b * 64];
    const int sL    = seg[b * 64 + 63];
    const int prevL = (b == 0) ? -1 : seg[b * 64 - 1];

    if (prevL < sF) {                 // b owns its first segment
        float p = partial[(size_t)(b * 2 + 0) * N_RANK + col];
        for (int b2 = b + 1; b2 < NB64 && seg[b2 * 64] == sF; ++b2)
            p *= partial[(size_t)(b2 * 2 + 0) * N_RANK + col];
        out[(size_t)sF * N_RANK + col] = p;
    }
    if (sL != sF) {                   // b always owns sL when sL != sF
        float p = partial[(size_t)(b * 2 + 1) * N_RANK + col];
        for (int b2 = b + 1; b2 < NB64 && seg[b2 * 64] == sL; ++b2)
            p *= partial[(size_t)(b2 * 2 + 0) * N_RANK + col];
        out[(size_t)sL * N_RANK + col] = p;
    }
}

extern "C" void kernel_launch(void* const* d_in, const int* in_sizes, int n_in,
                              void* d_out, int out_size, void* d_ws, size_t ws_size,
                              hipStream_t stream) {
    const float* x   = (const float*)d_in[0];
    const float* W   = (const float*)d_in[1];
    const float* b   = (const float*)d_in[2];
    const int*   seg = (const int*)d_in[3];
    float*       out = (float*)d_out;
    __hip_bfloat16* Wb = (__hip_bfloat16*)d_ws;                       // 256 KB
    float* partial = (float*)((char*)d_ws + (1 << 20));               // 4 MB @ +1MB

    prep_kernel<<<(NSEG * N_RANK) / 256, 256, 0, stream>>>(W, Wb, out);
    fused_kernel<<<NBLK, 512, 0, stream>>>(x, Wb, b, seg, out, partial);
    pass2_kernel<<<NB64, 256, 0, stream>>>(seg, partial, out);
}